// Round 1
// baseline (15544.218 us; speedup 1.0000x reference)
//
#include <hip/hip_runtime.h>
#include <math.h>

#define NBATCH 128
#define TSTEPS 128
#define DDIM   1024
#define HDIM   1024
#define FOURH  4096
#define KTOT   3072
#define KSPLIT 4
#define KCHUNK (KTOT / KSPLIT)   // 768
#define KC     32
#define BJ     64

// ---------------------------------------------------------------------------
// h0 = c0 = mean over the 16 spatial cells of A[n][h][0:16]
__global__ __launch_bounds__(256) void init_kernel(const float* __restrict__ A,
                                                   float* __restrict__ h,
                                                   float* __restrict__ c) {
    int idx = blockIdx.x * 256 + threadIdx.x;   // n*H + hh
    if (idx >= NBATCH * HDIM) return;
    const float4* a4 = reinterpret_cast<const float4*>(A + (size_t)idx * 16);
    float s = 0.f;
#pragma unroll
    for (int i = 0; i < 4; ++i) {
        float4 v = a4[i];
        s += v.x + v.y + v.z + v.w;
    }
    s *= (1.0f / 16.0f);
    h[idx] = s;
    c[idx] = s;
}

// ---------------------------------------------------------------------------
// Per-step attention: one block per batch row n.
// qk[k] = sum_h h[n,h]*A[n,h,k];  w = softmax(qk/32);  attn[n,h] = sum_k A[n,h,k]*w[k]
__global__ __launch_bounds__(256) void attn_kernel(const float* __restrict__ A,
                                                   const float* __restrict__ h,
                                                   float* __restrict__ attn) {
    int n = blockIdx.x;
    int tid = threadIdx.x;
    __shared__ float red[256][17];   // padded: conflict-free tree reduce

    float part[16];
#pragma unroll
    for (int k = 0; k < 16; ++k) part[k] = 0.f;

    const float* Arow = A + (size_t)n * HDIM * 16;
    const float* hrow = h + (size_t)n * HDIM;

    for (int hh = tid; hh < HDIM; hh += 256) {
        float hv = hrow[hh];
        const float4* a4 = reinterpret_cast<const float4*>(Arow + (size_t)hh * 16);
#pragma unroll
        for (int i = 0; i < 4; ++i) {
            float4 v = a4[i];
            part[4 * i + 0] += hv * v.x;
            part[4 * i + 1] += hv * v.y;
            part[4 * i + 2] += hv * v.z;
            part[4 * i + 3] += hv * v.w;
        }
    }
#pragma unroll
    for (int k = 0; k < 16; ++k) red[tid][k] = part[k];
    __syncthreads();
    for (int off = 128; off >= 1; off >>= 1) {
        if (tid < off) {
#pragma unroll
            for (int k = 0; k < 16; ++k) red[tid][k] += red[tid + off][k];
        }
        __syncthreads();
    }

    // softmax over 16 values, computed redundantly by every thread (broadcast reads)
    float w[16];
    float mx = -1e30f;
#pragma unroll
    for (int k = 0; k < 16; ++k) {
        w[k] = red[0][k] * 0.03125f;   // 1/sqrt(1024)
        mx = fmaxf(mx, w[k]);
    }
    float sum = 0.f;
#pragma unroll
    for (int k = 0; k < 16; ++k) {
        w[k] = __expf(w[k] - mx);
        sum += w[k];
    }
    float inv = 1.0f / sum;
#pragma unroll
    for (int k = 0; k < 16; ++k) w[k] *= inv;

    for (int hh = tid; hh < HDIM; hh += 256) {
        const float4* a4 = reinterpret_cast<const float4*>(Arow + (size_t)hh * 16);
        float s = 0.f;
#pragma unroll
        for (int i = 0; i < 4; ++i) {
            float4 v = a4[i];
            s += w[4 * i + 0] * v.x + w[4 * i + 1] * v.y + w[4 * i + 2] * v.z + w[4 * i + 3] * v.w;
        }
        attn[(size_t)n * HDIM + hh] = s;
    }
}

// ---------------------------------------------------------------------------
// Per-step GEMM: a_part[kc] = [x_t | h | attn][:, kc*768:(kc+1)*768] @ W[kc*768:..., :]
// Block tile: 128 rows x 64 cols, 256 threads, 8x4 outputs per thread.
// Grid: (4096/64, KSPLIT)
__global__ __launch_bounds__(256) void gemm_kernel(const float* __restrict__ x_t,   // row stride T*D
                                                   const float* __restrict__ h,     // N x H
                                                   const float* __restrict__ attn,  // N x H
                                                   const float* __restrict__ Wx,
                                                   const float* __restrict__ Wh,
                                                   const float* __restrict__ Wattn,
                                                   float* __restrict__ a_part) {    // KSPLIT x N x 4H
    __shared__ float As[128][KC + 1];
    __shared__ float Bs[KC][BJ + 1];

    int jb  = blockIdx.x * BJ;
    int kc  = blockIdx.y;
    int tid = threadIdx.x;
    int ty  = tid >> 4;   // 0..15
    int tx  = tid & 15;   // 0..15

    float acc[8][4];
#pragma unroll
    for (int i = 0; i < 8; ++i)
#pragma unroll
        for (int j = 0; j < 4; ++j) acc[i][j] = 0.f;

    int kbeg = kc * KCHUNK;
    int kend = kbeg + KCHUNK;

    for (int kb = kbeg; kb < kend; kb += KC) {
        // pick A source / W matrix for this 32-wide K tile (tiles never straddle segments)
        const float* Asrc;
        const float* Wp;
        size_t astr;
        int k0;
        if (kb < 1024)       { Asrc = x_t;  astr = (size_t)TSTEPS * DDIM; Wp = Wx;    k0 = kb; }
        else if (kb < 2048)  { Asrc = h;    astr = HDIM;                  Wp = Wh;    k0 = kb - 1024; }
        else                 { Asrc = attn; astr = HDIM;                  Wp = Wattn; k0 = kb - 2048; }

        for (int i = tid; i < 128 * KC; i += 256) {
            int r  = i >> 5;
            int kk = i & (KC - 1);
            As[r][kk] = Asrc[(size_t)r * astr + k0 + kk];
        }
        for (int i = tid; i < KC * BJ; i += 256) {
            int kk = i >> 6;
            int cc = i & (BJ - 1);
            Bs[kk][cc] = Wp[(size_t)(k0 + kk) * FOURH + jb + cc];
        }
        __syncthreads();

#pragma unroll
        for (int kk = 0; kk < KC; ++kk) {
            float av[8], bv[4];
#pragma unroll
            for (int i = 0; i < 8; ++i) av[i] = As[ty * 8 + i][kk];
#pragma unroll
            for (int j = 0; j < 4; ++j) bv[j] = Bs[kk][tx * 4 + j];
#pragma unroll
            for (int i = 0; i < 8; ++i)
#pragma unroll
                for (int j = 0; j < 4; ++j) acc[i][j] += av[i] * bv[j];
        }
        __syncthreads();
    }

    float* arow = a_part + (size_t)kc * NBATCH * FOURH;
#pragma unroll
    for (int i = 0; i < 8; ++i) {
        int r = ty * 8 + i;
#pragma unroll
        for (int j = 0; j < 4; ++j) {
            int cc = jb + tx * 4 + j;
            arow[(size_t)r * FOURH + cc] = acc[i][j];
        }
    }
}

// ---------------------------------------------------------------------------
// Gates: sum K-split partials + bias, apply LSTM cell, write h/c/out
__global__ __launch_bounds__(256) void gate_kernel(const float* __restrict__ a_part,
                                                   const float* __restrict__ bias,
                                                   float* __restrict__ h,
                                                   float* __restrict__ c,
                                                   float* __restrict__ out_t) {  // out + t*H, row stride T*H
    int idx = blockIdx.x * 256 + threadIdx.x;
    if (idx >= NBATCH * HDIM) return;
    int n  = idx >> 10;
    int hh = idx & 1023;

    float ai = bias[hh];
    float af = bias[1024 + hh];
    float ao = bias[2048 + hh];
    float ag = bias[3072 + hh];
#pragma unroll
    for (int kc = 0; kc < KSPLIT; ++kc) {
        const float* arow = a_part + ((size_t)kc * NBATCH + n) * FOURH;
        ai += arow[hh];
        af += arow[1024 + hh];
        ao += arow[2048 + hh];
        ag += arow[3072 + hh];
    }

    float si = 1.f / (1.f + __expf(-ai));
    float sf = 1.f / (1.f + __expf(-af));
    float so = 1.f / (1.f + __expf(-ao));
    float tg = tanhf(ag);
    float cn = sf * c[idx] + si * tg;
    float hn = so * tanhf(cn);
    c[idx] = cn;
    h[idx] = hn;
    out_t[(size_t)n * (TSTEPS * HDIM) + hh] = hn;
}

// ---------------------------------------------------------------------------
extern "C" void kernel_launch(void* const* d_in, const int* in_sizes, int n_in,
                              void* d_out, int out_size, void* d_ws, size_t ws_size,
                              hipStream_t stream) {
    const float* x     = (const float*)d_in[0];
    const float* A     = (const float*)d_in[1];
    const float* Wx    = (const float*)d_in[2];
    const float* Wh    = (const float*)d_in[3];
    const float* Wattn = (const float*)d_in[4];
    const float* b     = (const float*)d_in[5];
    float* out = (float*)d_out;

    float* h_buf    = (float*)d_ws;                       // N*H
    float* c_buf    = h_buf + NBATCH * HDIM;              // N*H
    float* attn_buf = c_buf + NBATCH * HDIM;              // N*H
    float* a_buf    = attn_buf + NBATCH * HDIM;           // KSPLIT*N*4H

    init_kernel<<<(NBATCH * HDIM + 255) / 256, 256, 0, stream>>>(A, h_buf, c_buf);

    for (int t = 0; t < TSTEPS; ++t) {
        attn_kernel<<<NBATCH, 256, 0, stream>>>(A, h_buf, attn_buf);
        gemm_kernel<<<dim3(FOURH / BJ, KSPLIT), 256, 0, stream>>>(
            x + (size_t)t * DDIM, h_buf, attn_buf, Wx, Wh, Wattn, a_buf);
        gate_kernel<<<(NBATCH * HDIM + 255) / 256, 256, 0, stream>>>(
            a_buf, b, h_buf, c_buf, out + (size_t)t * HDIM);
    }
}

// Round 2
// 3146.394 us; speedup vs baseline: 4.9403x; 4.9403x over previous
//
#include <hip/hip_runtime.h>
#include <math.h>

#define NB 128
#define TT 128
#define HD 1024
#define FH 4096
#define KT3 3072

typedef __attribute__((ext_vector_type(8))) short short8v;
typedef __attribute__((ext_vector_type(4))) float float4v;

__device__ __forceinline__ ushort f2b(float f) {
    union { float f; unsigned u; } v; v.f = f;
    unsigned r = (v.u + 0x7fffu + ((v.u >> 16) & 1u)) >> 16;
    return (ushort)r;
}

__device__ __forceinline__ void gll16(const void* g, void* l) {
    __builtin_amdgcn_global_load_lds(
        (const __attribute__((address_space(1))) void*)g,
        (__attribute__((address_space(3))) void*)l,
        16, 0, 0);
}

// ---------------------------------------------------------------------------
// x fp32 -> bf16, 8 elems/thread
__global__ __launch_bounds__(256) void cvt_x(const float* __restrict__ x,
                                             ushort* __restrict__ xb) {
    size_t i = (size_t)blockIdx.x * 256 + threadIdx.x;   // 2,097,152 groups of 8
    const float4* p = (const float4*)x + i * 2;
    float4 va = p[0], vb = p[1];
    union { ushort u[8]; uint4 v; } o;
    o.u[0] = f2b(va.x); o.u[1] = f2b(va.y); o.u[2] = f2b(va.z); o.u[3] = f2b(va.w);
    o.u[4] = f2b(vb.x); o.u[5] = f2b(vb.y); o.u[6] = f2b(vb.z); o.u[7] = f2b(vb.w);
    ((uint4*)xb)[i] = o.v;
}

// ---------------------------------------------------------------------------
// WT[n][k] = W_seg[k][n] in bf16.  k<1024: Wx, <2048: Wh, else Wattn.
__global__ __launch_bounds__(256) void build_wt(const float* __restrict__ Wx,
                                                const float* __restrict__ Wh,
                                                const float* __restrict__ Wattn,
                                                ushort* __restrict__ WT) {
    __shared__ ushort Ls[64][65];
    int k0 = blockIdx.x * 64, n0 = blockIdx.y * 64;
    const float* W; int kk0;
    if (k0 < 1024)      { W = Wx;    kk0 = k0; }
    else if (k0 < 2048) { W = Wh;    kk0 = k0 - 1024; }
    else                { W = Wattn; kk0 = k0 - 2048; }
    int t = threadIdx.x;
    int cc = t & 63, r4 = t >> 6;
#pragma unroll
    for (int i = 0; i < 16; ++i) {
        int r = i * 4 + r4;
        Ls[r][cc] = f2b(W[(size_t)(kk0 + r) * FH + n0 + cc]);
    }
    __syncthreads();
#pragma unroll
    for (int i = 0; i < 16; ++i) {
        int nn = i * 4 + r4;
        WT[(size_t)(n0 + nn) * KT3 + k0 + cc] = Ls[cc][nn];
    }
}

// ---------------------------------------------------------------------------
// swizzled 16B chunk helpers: logical chunk lc at row r lives in slot
// (lc&8) | ((lc&7) ^ (r&7)); involution, applied on both stage and read.
__device__ __forceinline__ short8v ldfrag(const ushort* base, int row, int ch) {
    int slot = (ch & 8) | ((ch & 7) ^ (row & 7));
    return *(const short8v*)(base + row * 128 + slot * 8);
}

__device__ __forceinline__ void stage_tile(const ushort* __restrict__ xb_t,
                                           const ushort* __restrict__ hattn,
                                           const ushort* __restrict__ WT,
                                           ushort* Ab, ushort* Bb,
                                           int bm0, int n0, int kt, int w, int l) {
    const ushort* asrc; size_t astr; int kloc;
    if (kt < 1024) { asrc = xb_t;  astr = (size_t)TT * HD; kloc = kt; }
    else           { asrc = hattn; astr = 2048;            kloc = kt - 1024; }
#pragma unroll
    for (int ci = 0; ci < 2; ++ci) {           // A: 32 rows x 16 chunks = 512
        int s = ((ci * 4 + w) << 6) + l;
        int r = s >> 4, cc = s & 15;
        int lc = (cc & 8) | ((cc & 7) ^ (r & 7));
        gll16(asrc + (size_t)(bm0 + r) * astr + kloc + lc * 8,
              Ab + ((ci * 4 + w) << 9));
    }
#pragma unroll
    for (int ci = 0; ci < 4; ++ci) {           // B: 64 rows x 16 chunks = 1024
        int s = ((ci * 4 + w) << 6) + l;
        int rn = s >> 4, cc = s & 15;
        int lc = (cc & 8) | ((cc & 7) ^ (rn & 7));
        gll16(WT + (size_t)(n0 + rn) * KT3 + kt + lc * 8,
              Bb + ((ci * 4 + w) << 9));
    }
}

// ---------------------------------------------------------------------------
// a_part[ks] = Ain[:, ks*1536:(ks+1)*1536] @ W[...]  (bf16 MFMA, fp32 acc)
// grid (64 ncol, 2 ksplit, 4 mrow); block 256 = 4 waves along N.
__global__ __launch_bounds__(256, 2) void gemm_kernel(
    const ushort* __restrict__ xb_t,    // + t*HD, row stride TT*HD
    const ushort* __restrict__ hattn,   // [128][2048]
    const ushort* __restrict__ WT,      // [4096][3072]
    float* __restrict__ a_part)         // [2][128][4096]
{
    __shared__ alignas(16) ushort As[2][32 * 128];
    __shared__ alignas(16) ushort Bs[2][64 * 128];

    const int w   = threadIdx.x >> 6;
    const int l   = threadIdx.x & 63;
    const int n0  = blockIdx.x * 64;
    const int ks  = blockIdx.y;
    const int bm0 = blockIdx.z * 32;
    const int kbase = ks * 1536;
    const int lr = l & 15, g = l >> 4;

    float4v acc0 = {0.f, 0.f, 0.f, 0.f};
    float4v acc1 = {0.f, 0.f, 0.f, 0.f};

    stage_tile(xb_t, hattn, WT, As[0], Bs[0], bm0, n0, kbase, w, l);
    __syncthreads();

    int cur = 0;
    for (int it = 0; it < 12; ++it) {
        if (it + 1 < 12)
            stage_tile(xb_t, hattn, WT, As[cur ^ 1], Bs[cur ^ 1],
                       bm0, n0, kbase + (it + 1) * 128, w, l);
        const ushort* Ab = As[cur];
        const ushort* Bb = Bs[cur];
#pragma unroll
        for (int ko = 0; ko < 4; ++ko) {
            int chb = ko * 4;
            short8v bf = ldfrag(Bb, w * 16 + lr, chb + g);
            short8v a0 = ldfrag(Ab, lr,          chb + g);
            short8v a1 = ldfrag(Ab, 16 + lr,     chb + g);
            acc0 = __builtin_amdgcn_mfma_f32_16x16x32_bf16(a0, bf, acc0, 0, 0, 0);
            acc1 = __builtin_amdgcn_mfma_f32_16x16x32_bf16(a1, bf, acc1, 0, 0, 0);
        }
        __syncthreads();   // drains this iter's prefetch loads + guards buffer reuse
        cur ^= 1;
    }

    float* dst = a_part + (size_t)ks * (NB * FH);
    const int col = n0 + w * 16 + lr;
#pragma unroll
    for (int j = 0; j < 4; ++j) {
        dst[(size_t)(bm0 + g * 4 + j) * FH + col]      = acc0[j];
        dst[(size_t)(bm0 + 16 + g * 4 + j) * FH + col] = acc1[j];
    }
}

// ---------------------------------------------------------------------------
// MODE 0: h0=c0=meanpool(A) then attention.  MODE 1: gates(a)+cell, out, attn.
// 1 block per batch row, 1024 threads (thread = h index).
template <int MODE>
__global__ __launch_bounds__(1024) void fused_kernel(
    const float* __restrict__ a_part,   // [2][128][4096]
    const float* __restrict__ bias,     // [4096]
    const float* __restrict__ A,        // [128][1024][16]
    float* __restrict__ c,              // [128][1024]
    ushort* __restrict__ hattn,         // [128][2048] bf16 (h | attn)
    float* __restrict__ out_t)          // + t*HD, row stride TT*HD
{
    __shared__ float red[16][17];
    const int n = blockIdx.x, hh = threadIdx.x;
    const size_t idx = (size_t)n * HD + hh;
    const float4* a4 = (const float4*)(A + idx * 16);
    float4 A0 = a4[0], A1 = a4[1], A2 = a4[2], A3 = a4[3];

    float hv;
    if (MODE == 0) {
        float s = A0.x + A0.y + A0.z + A0.w + A1.x + A1.y + A1.z + A1.w
                + A2.x + A2.y + A2.z + A2.w + A3.x + A3.y + A3.z + A3.w;
        hv = s * 0.0625f;
        c[idx] = hv;
    } else {
        const size_t ab = (size_t)n * FH + hh;
        const float* ap0 = a_part;
        const float* ap1 = a_part + (size_t)NB * FH;
        float ai = bias[hh]        + ap0[ab]        + ap1[ab];
        float af = bias[1024 + hh] + ap0[ab + 1024] + ap1[ab + 1024];
        float ao = bias[2048 + hh] + ap0[ab + 2048] + ap1[ab + 2048];
        float ag = bias[3072 + hh] + ap0[ab + 3072] + ap1[ab + 3072];
        float si = 1.f / (1.f + __expf(-ai));
        float sf = 1.f / (1.f + __expf(-af));
        float so = 1.f / (1.f + __expf(-ao));
        float tg = tanhf(ag);
        float cn = sf * c[idx] + si * tg;
        hv = so * tanhf(cn);
        c[idx] = cn;
        out_t[(size_t)n * (TT * HD) + hh] = hv;
    }
    hattn[(size_t)n * 2048 + hh] = f2b(hv);

    // attention scores: qk[k] = sum_h h*A[n][h][k]
    float p[16];
    p[0]  = hv * A0.x; p[1]  = hv * A0.y; p[2]  = hv * A0.z; p[3]  = hv * A0.w;
    p[4]  = hv * A1.x; p[5]  = hv * A1.y; p[6]  = hv * A1.z; p[7]  = hv * A1.w;
    p[8]  = hv * A2.x; p[9]  = hv * A2.y; p[10] = hv * A2.z; p[11] = hv * A2.w;
    p[12] = hv * A3.x; p[13] = hv * A3.y; p[14] = hv * A3.z; p[15] = hv * A3.w;
#pragma unroll
    for (int k = 0; k < 16; ++k) {
        float v = p[k];
        v += __shfl_xor(v, 32); v += __shfl_xor(v, 16); v += __shfl_xor(v, 8);
        v += __shfl_xor(v, 4);  v += __shfl_xor(v, 2);  v += __shfl_xor(v, 1);
        p[k] = v;
    }
    const int wv = hh >> 6;
    if ((hh & 63) == 0) {
#pragma unroll
        for (int k = 0; k < 16; ++k) red[wv][k] = p[k];
    }
    __syncthreads();
    float qk[16], mx = -1e30f;
#pragma unroll
    for (int k = 0; k < 16; ++k) {
        float s = 0.f;
#pragma unroll
        for (int w2 = 0; w2 < 16; ++w2) s += red[w2][k];
        qk[k] = s * 0.03125f;             // 1/sqrt(1024)
        mx = fmaxf(mx, qk[k]);
    }
    float sum = 0.f;
#pragma unroll
    for (int k = 0; k < 16; ++k) { qk[k] = __expf(qk[k] - mx); sum += qk[k]; }
    float inv = 1.f / sum;
    float av = qk[0]*A0.x + qk[1]*A0.y + qk[2]*A0.z + qk[3]*A0.w
             + qk[4]*A1.x + qk[5]*A1.y + qk[6]*A1.z + qk[7]*A1.w
             + qk[8]*A2.x + qk[9]*A2.y + qk[10]*A2.z + qk[11]*A2.w
             + qk[12]*A3.x + qk[13]*A3.y + qk[14]*A3.z + qk[15]*A3.w;
    av *= inv;
    hattn[(size_t)n * 2048 + 1024 + hh] = f2b(av);
}

// ---------------------------------------------------------------------------
extern "C" void kernel_launch(void* const* d_in, const int* in_sizes, int n_in,
                              void* d_out, int out_size, void* d_ws, size_t ws_size,
                              hipStream_t stream) {
    const float* x     = (const float*)d_in[0];
    const float* A     = (const float*)d_in[1];
    const float* Wx    = (const float*)d_in[2];
    const float* Wh    = (const float*)d_in[3];
    const float* Wattn = (const float*)d_in[4];
    const float* b     = (const float*)d_in[5];
    float* out = (float*)d_out;

    ushort* WT    = (ushort*)d_ws;                        // 4096*3072 bf16 = 25.2 MB
    ushort* xb    = WT + (size_t)FH * KT3;                // 128*128*1024 bf16 = 33.6 MB
    ushort* hattn = xb + (size_t)NB * TT * HD;            // 128*2048 bf16
    float*  c_buf = (float*)(hattn + (size_t)NB * 2048);  // 128*1024 fp32
    float*  a_prt = c_buf + (size_t)NB * HD;              // 2*128*4096 fp32 = 4 MB

    cvt_x<<<8192, 256, 0, stream>>>(x, xb);
    build_wt<<<dim3(48, 64), 256, 0, stream>>>(Wx, Wh, Wattn, WT);
    fused_kernel<0><<<NB, 1024, 0, stream>>>(a_prt, b, A, c_buf, hattn, out);

    for (int t = 0; t < TT; ++t) {
        gemm_kernel<<<dim3(64, 2, 4), 256, 0, stream>>>(
            xb + (size_t)t * HD, hattn, WT, a_prt);
        fused_kernel<1><<<NB, 1024, 0, stream>>>(
            a_prt, b, A, c_buf, hattn, out + (size_t)t * HD);
    }
}